// Round 2
// baseline (680.525 us; speedup 1.0000x reference)
//
#include <hip/hip_runtime.h>

constexpr int BSZ = 8, SEQ = 4096, HID = 1024, NE = 8, CAP = 512;
constexpr int ROWS = BSZ * NE;                          // 64
constexpr size_t IDX_ELEMS = (size_t)ROWS * CAP;        // 32768
constexpr size_t SCR_OFF = IDX_ELEMS;                   // 32768
constexpr size_t MASK_OFF = IDX_ELEMS * 2;              // 65536
constexpr size_t MASK_ELEMS = (size_t)ROWS * CAP * SEQ; // 134217728
constexpr size_t AFF_ELEMS = (size_t)ROWS * SEQ;        // 262144 floats (1 MB)

// ---------------------------------------------------------------------------
// Gating — BYTE-IDENTICAL to the kernel that passed absmax=0. DO NOT TOUCH
// the arithmetic: np.einsum fp32 SOP emulation (4-lane accumulator, blocks of
// 16, x4-unrolled reversed chained mul+add, no FMA, SSE3 double-hadd hsum),
// softmax via max / fsub / correctly-rounded fp32 exp (through double) /
// pairwise-8 tree sum / fp32 div.
// ---------------------------------------------------------------------------
__global__ __launch_bounds__(128) void gating_kernel(const float* __restrict__ hidden,
                                                     const float* __restrict__ weight,
                                                     float* __restrict__ aff)
{
    __shared__ float hls[16][68]; // 16 tokens x 64-d chunk (pad to 68)
    __shared__ float wls[8][68];  // transposed weight chunk: [e][dd]
    __shared__ float lls[16][8];  // logits exchange

    const int tid = threadIdx.x;
    const int T0 = blockIdx.x * 16;
    const int t = tid >> 3;       // token within block
    const int e = tid & 7;        // expert

    float v0 = 0.f, v1 = 0.f, v2 = 0.f, v3 = 0.f; // SSE lanes j=0..3
    for (int c = 0; c < 16; ++c) {
        __syncthreads(); // protect previous chunk's reads
        // stage hidden chunk: 256 float4s, coalesced
#pragma unroll
        for (int k = 0; k < 2; ++k) {
            const int j = tid + k * 128;      // 0..255
            const int tt = j >> 4, q = j & 15;
            const float4 v = *(const float4*)(hidden + (size_t)(T0 + tt) * HID + c * 64 + 4 * q);
            *(float4*)&hls[tt][4 * q] = v;
        }
        // stage weight chunk transposed: 512 scalars, coalesced global reads
#pragma unroll
        for (int k = 0; k < 4; ++k) {
            const int j = tid + k * 128;      // 0..511 == dd*8+ee
            const int dd = j >> 3, ee = j & 7;
            wls[ee][dd] = weight[(size_t)(c * 64 + dd) * NE + ee];
        }
        __syncthreads();
        // four 16-float blocks per chunk, numpy SOP order
#pragma unroll
        for (int k = 0; k < 4; ++k) {
            const int base = 16 * k;
            const float4 hA = *(const float4*)&hls[t][base + 0];
            const float4 hB = *(const float4*)&hls[t][base + 4];
            const float4 hC = *(const float4*)&hls[t][base + 8];
            const float4 hD = *(const float4*)&hls[t][base + 12];
            const float4 wA = *(const float4*)&wls[e][base + 0];
            const float4 wB = *(const float4*)&wls[e][base + 4];
            const float4 wC = *(const float4*)&wls[e][base + 8];
            const float4 wD = *(const float4*)&wls[e][base + 12];
            // v = a0*b0 + (a1*b1 + (a2*b2 + (a3*b3 + v))), per lane, no FMA
            v0 = __fadd_rn(__fmul_rn(hA.x, wA.x),
                 __fadd_rn(__fmul_rn(hB.x, wB.x),
                 __fadd_rn(__fmul_rn(hC.x, wC.x),
                 __fadd_rn(__fmul_rn(hD.x, wD.x), v0))));
            v1 = __fadd_rn(__fmul_rn(hA.y, wA.y),
                 __fadd_rn(__fmul_rn(hB.y, wB.y),
                 __fadd_rn(__fmul_rn(hC.y, wC.y),
                 __fadd_rn(__fmul_rn(hD.y, wD.y), v1))));
            v2 = __fadd_rn(__fmul_rn(hA.z, wA.z),
                 __fadd_rn(__fmul_rn(hB.z, wB.z),
                 __fadd_rn(__fmul_rn(hC.z, wC.z),
                 __fadd_rn(__fmul_rn(hD.z, wD.z), v2))));
            v3 = __fadd_rn(__fmul_rn(hA.w, wA.w),
                 __fadd_rn(__fmul_rn(hB.w, wB.w),
                 __fadd_rn(__fmul_rn(hC.w, wC.w),
                 __fadd_rn(__fmul_rn(hD.w, wD.w), v3))));
        }
    }
    // npyv_sum_f32 with SSE3 (manylinux baseline): double hadd = (v0+v1)+(v2+v3)
    const float logit = __fadd_rn(__fadd_rn(v0, v1), __fadd_rn(v2, v3));

    lls[t][e] = logit;
    __syncthreads();

    float l[8];
#pragma unroll
    for (int k = 0; k < 8; ++k) l[k] = lls[t][k];
    float m = l[0];
#pragma unroll
    for (int k = 1; k < 8; ++k) m = fmaxf(m, l[k]);
    float p[8];
#pragma unroll
    for (int k = 0; k < 8; ++k)
        p[k] = (float)exp((double)__fsub_rn(l[k], m)); // correctly-rounded fp32 exp
    const float s = __fadd_rn(__fadd_rn(__fadd_rn(p[0], p[1]), __fadd_rn(p[2], p[3])),
                              __fadd_rn(__fadd_rn(p[4], p[5]), __fadd_rn(p[6], p[7])));
    const float a = __fdiv_rn(p[e], s);

    const int token = T0 + t;
    const int b = token >> 12;
    const int sidx = token & (SEQ - 1);
    aff[((size_t)b * NE + e) * SEQ + sidx] = a;
}

// ---------------------------------------------------------------------------
// Top-k: sort-only (64 blocks). Bitonic CE order, key packing, and the
// index/score stores are byte-identical to the verified kernel. The mask
// zeroing moved to mask_kernel (dense one-hot pass).
// ---------------------------------------------------------------------------
__global__ __launch_bounds__(1024) void topk_kernel(const float* __restrict__ aff,
                                                    float* __restrict__ out)
{
    __shared__ unsigned long long keys[SEQ]; // 32 KB
    const int row = blockIdx.x;
    const float* a = aff + (size_t)row * SEQ;
    for (int i = threadIdx.x; i < SEQ; i += 1024) {
        const unsigned int fb = __float_as_uint(a[i]);
        keys[i] = ((unsigned long long)fb << 32) | (unsigned int)(SEQ - 1 - i);
    }
    for (int len = 2; len <= SEQ; len <<= 1) {
        for (int stride = len >> 1; stride > 0; stride >>= 1) {
            __syncthreads();
            for (int t = threadIdx.x; t < SEQ / 2; t += 1024) {
                const int i = (t << 1) - (t & (stride - 1));
                const int j = i + stride;
                const unsigned long long ki = keys[i], kj = keys[j];
                const bool desc = ((i & len) == 0);
                if (desc ? (ki < kj) : (ki > kj)) { keys[i] = kj; keys[j] = ki; }
            }
        }
    }
    __syncthreads();
    if (threadIdx.x < CAP) {
        const int t = threadIdx.x;
        const unsigned long long k = keys[t];
        const int idx = (SEQ - 1) - (int)(unsigned int)(k & 0xffffffffu);
        out[(size_t)row * CAP + t] = (float)idx;                         // indices
        out[SCR_OFF + (size_t)row * CAP + t] =
            __uint_as_float((unsigned int)(k >> 32));                    // scores
    }
}

// ---------------------------------------------------------------------------
// Dense one-hot mask write: single streamed pass over all 512 MB, placing the
// 1.0f inline via compare-select. Replaces {grid-stride zero + scattered
// partial-line RMW stores + tailzero}. Access pattern == fillBuffer (proven
// 6.2 TB/s on this harness): per wave-iteration, 64 lanes store 4 KB
// contiguous float4s. Each block owns 4 cap-rows (4 x 16 KB).
// ---------------------------------------------------------------------------
__global__ __launch_bounds__(256) void mask_kernel(const float* __restrict__ idxf,
                                                   float* __restrict__ mask)
{
    const int t = threadIdx.x;
    const int r0 = blockIdx.x * 4;
#pragma unroll
    for (int r = 0; r < 4; ++r) {
        const int rc = r0 + r;                     // cap-row id 0..32767
        const int idx = (int)idxf[rc];             // uniform -> scalar load
        float* dst = mask + (size_t)rc * SEQ;
#pragma unroll
        for (int k = 0; k < 4; ++k) {
            const int pos = (k * 256 + t) * 4;     // float index of this float4
            float4 v;
            v.x = (idx == pos + 0) ? 1.0f : 0.0f;
            v.y = (idx == pos + 1) ? 1.0f : 0.0f;
            v.z = (idx == pos + 2) ? 1.0f : 0.0f;
            v.w = (idx == pos + 3) ? 1.0f : 0.0f;
            *(float4*)(dst + pos) = v;
        }
    }
}

extern "C" void kernel_launch(void* const* d_in, const int* in_sizes, int n_in,
                              void* d_out, int out_size, void* d_ws, size_t ws_size,
                              hipStream_t stream)
{
    const float* hidden = (const float*)d_in[0];
    const float* weight = (const float*)d_in[1];
    float* out = (float*)d_out;

    // Affinity scratch [b][e][s] fp32 = 1 MB. Prefer d_ws; else borrow the
    // mask tail. The borrow is safe without any tail re-zero now: topk reads
    // it, then mask_kernel's dense pass overwrites the entire mask region.
    const bool use_ws = (ws_size >= AFF_ELEMS * sizeof(float));
    float* aff = use_ws ? (float*)d_ws
                        : (out + MASK_OFF + MASK_ELEMS - AFF_ELEMS);

    gating_kernel<<<2048, 128, 0, stream>>>(hidden, weight, aff);

    topk_kernel<<<ROWS, 1024, 0, stream>>>(aff, out);

    mask_kernel<<<(int)(IDX_ELEMS / 4), 256, 0, stream>>>(out, out + MASK_OFF);
}

// Round 3
// 654.436 us; speedup vs baseline: 1.0399x; 1.0399x over previous
//
#include <hip/hip_runtime.h>

constexpr int BSZ = 8, SEQ = 4096, HID = 1024, NE = 8, CAP = 512;
constexpr int ROWS = BSZ * NE;                          // 64
constexpr size_t IDX_ELEMS = (size_t)ROWS * CAP;        // 32768
constexpr size_t SCR_OFF = IDX_ELEMS;                   // 32768
constexpr size_t MASK_OFF = IDX_ELEMS * 2;              // 65536
constexpr size_t MASK_ELEMS = (size_t)ROWS * CAP * SEQ; // 134217728
constexpr size_t AFF_ELEMS = (size_t)ROWS * SEQ;        // 262144 floats (1 MB)

typedef float f4v __attribute__((ext_vector_type(4)));  // for nontemporal stores

// ---------------------------------------------------------------------------
// Gating — BYTE-IDENTICAL to the kernel that passed absmax=0. DO NOT TOUCH
// the arithmetic: np.einsum fp32 SOP emulation (4-lane accumulator, blocks of
// 16, x4-unrolled reversed chained mul+add, no FMA, SSE3 double-hadd hsum),
// softmax via max / fsub / correctly-rounded fp32 exp (through double) /
// pairwise-8 tree sum / fp32 div.
// ---------------------------------------------------------------------------
__global__ __launch_bounds__(128) void gating_kernel(const float* __restrict__ hidden,
                                                     const float* __restrict__ weight,
                                                     float* __restrict__ aff)
{
    __shared__ float hls[16][68]; // 16 tokens x 64-d chunk (pad to 68)
    __shared__ float wls[8][68];  // transposed weight chunk: [e][dd]
    __shared__ float lls[16][8];  // logits exchange

    const int tid = threadIdx.x;
    const int T0 = blockIdx.x * 16;
    const int t = tid >> 3;       // token within block
    const int e = tid & 7;        // expert

    float v0 = 0.f, v1 = 0.f, v2 = 0.f, v3 = 0.f; // SSE lanes j=0..3
    for (int c = 0; c < 16; ++c) {
        __syncthreads(); // protect previous chunk's reads
        // stage hidden chunk: 256 float4s, coalesced
#pragma unroll
        for (int k = 0; k < 2; ++k) {
            const int j = tid + k * 128;      // 0..255
            const int tt = j >> 4, q = j & 15;
            const float4 v = *(const float4*)(hidden + (size_t)(T0 + tt) * HID + c * 64 + 4 * q);
            *(float4*)&hls[tt][4 * q] = v;
        }
        // stage weight chunk transposed: 512 scalars, coalesced global reads
#pragma unroll
        for (int k = 0; k < 4; ++k) {
            const int j = tid + k * 128;      // 0..511 == dd*8+ee
            const int dd = j >> 3, ee = j & 7;
            wls[ee][dd] = weight[(size_t)(c * 64 + dd) * NE + ee];
        }
        __syncthreads();
        // four 16-float blocks per chunk, numpy SOP order
#pragma unroll
        for (int k = 0; k < 4; ++k) {
            const int base = 16 * k;
            const float4 hA = *(const float4*)&hls[t][base + 0];
            const float4 hB = *(const float4*)&hls[t][base + 4];
            const float4 hC = *(const float4*)&hls[t][base + 8];
            const float4 hD = *(const float4*)&hls[t][base + 12];
            const float4 wA = *(const float4*)&wls[e][base + 0];
            const float4 wB = *(const float4*)&wls[e][base + 4];
            const float4 wC = *(const float4*)&wls[e][base + 8];
            const float4 wD = *(const float4*)&wls[e][base + 12];
            // v = a0*b0 + (a1*b1 + (a2*b2 + (a3*b3 + v))), per lane, no FMA
            v0 = __fadd_rn(__fmul_rn(hA.x, wA.x),
                 __fadd_rn(__fmul_rn(hB.x, wB.x),
                 __fadd_rn(__fmul_rn(hC.x, wC.x),
                 __fadd_rn(__fmul_rn(hD.x, wD.x), v0))));
            v1 = __fadd_rn(__fmul_rn(hA.y, wA.y),
                 __fadd_rn(__fmul_rn(hB.y, wB.y),
                 __fadd_rn(__fmul_rn(hC.y, wC.y),
                 __fadd_rn(__fmul_rn(hD.y, wD.y), v1))));
            v2 = __fadd_rn(__fmul_rn(hA.z, wA.z),
                 __fadd_rn(__fmul_rn(hB.z, wB.z),
                 __fadd_rn(__fmul_rn(hC.z, wC.z),
                 __fadd_rn(__fmul_rn(hD.z, wD.z), v2))));
            v3 = __fadd_rn(__fmul_rn(hA.w, wA.w),
                 __fadd_rn(__fmul_rn(hB.w, wB.w),
                 __fadd_rn(__fmul_rn(hC.w, wC.w),
                 __fadd_rn(__fmul_rn(hD.w, wD.w), v3))));
        }
    }
    // npyv_sum_f32 with SSE3 (manylinux baseline): double hadd = (v0+v1)+(v2+v3)
    const float logit = __fadd_rn(__fadd_rn(v0, v1), __fadd_rn(v2, v3));

    lls[t][e] = logit;
    __syncthreads();

    float l[8];
#pragma unroll
    for (int k = 0; k < 8; ++k) l[k] = lls[t][k];
    float m = l[0];
#pragma unroll
    for (int k = 1; k < 8; ++k) m = fmaxf(m, l[k]);
    float p[8];
#pragma unroll
    for (int k = 0; k < 8; ++k)
        p[k] = (float)exp((double)__fsub_rn(l[k], m)); // correctly-rounded fp32 exp
    const float s = __fadd_rn(__fadd_rn(__fadd_rn(p[0], p[1]), __fadd_rn(p[2], p[3])),
                              __fadd_rn(__fadd_rn(p[4], p[5]), __fadd_rn(p[6], p[7])));
    const float a = __fdiv_rn(p[e], s);

    const int token = T0 + t;
    const int b = token >> 12;
    const int sidx = token & (SEQ - 1);
    aff[((size_t)b * NE + e) * SEQ + sidx] = a;
}

// ---------------------------------------------------------------------------
// Fused top-k + zero-fill — the proven-650µs overlap structure (zero runs on
// 1984 blocks concurrently with the 64 sort blocks). ONLY change vs the
// verified version: the zero loop uses NONTEMPORAL float4 stores to avoid
// read-for-ownership (fillBuffer's 6.2 TB/s pattern). Value-neutral.
// ---------------------------------------------------------------------------
__global__ __launch_bounds__(1024) void topk_zero_kernel(const float* __restrict__ aff,
                                                         float* __restrict__ out,
                                                         long long zero_elems)
{
    __shared__ unsigned long long keys[SEQ]; // 32 KB
    if (blockIdx.x < (unsigned)ROWS) {
        const int row = blockIdx.x;
        const float* a = aff + (size_t)row * SEQ;
        for (int i = threadIdx.x; i < SEQ; i += 1024) {
            const unsigned int fb = __float_as_uint(a[i]);
            keys[i] = ((unsigned long long)fb << 32) | (unsigned int)(SEQ - 1 - i);
        }
        for (int len = 2; len <= SEQ; len <<= 1) {
            for (int stride = len >> 1; stride > 0; stride >>= 1) {
                __syncthreads();
                for (int t = threadIdx.x; t < SEQ / 2; t += 1024) {
                    const int i = (t << 1) - (t & (stride - 1));
                    const int j = i + stride;
                    const unsigned long long ki = keys[i], kj = keys[j];
                    const bool desc = ((i & len) == 0);
                    if (desc ? (ki < kj) : (ki > kj)) { keys[i] = kj; keys[j] = ki; }
                }
            }
        }
        __syncthreads();
        if (threadIdx.x < CAP) {
            const int t = threadIdx.x;
            const unsigned long long k = keys[t];
            const int idx = (SEQ - 1) - (int)(unsigned int)(k & 0xffffffffu);
            out[(size_t)row * CAP + t] = (float)idx;                         // indices
            out[SCR_OFF + (size_t)row * CAP + t] =
                __uint_as_float((unsigned int)(k >> 32));                    // scores
        }
    } else {
        const long long nz4 = zero_elems >> 2;
        f4v* mz = (f4v*)(out + MASK_OFF);
        const f4v z4 = {0.f, 0.f, 0.f, 0.f};
        const long long stride = (long long)(gridDim.x - ROWS) * 1024;
        for (long long i = (long long)(blockIdx.x - ROWS) * 1024 + threadIdx.x;
             i < nz4; i += stride)
            __builtin_nontemporal_store(z4, mz + i);
    }
}

// Fallback-path helper: re-zero the mask tail that temporarily held affinity.
__global__ void tailzero_kernel(float* __restrict__ out)
{
    const long long n4 = (long long)(AFF_ELEMS >> 2); // 65536 float4s
    f4v* mz = (f4v*)(out + MASK_OFF + MASK_ELEMS - AFF_ELEMS);
    const f4v z4 = {0.f, 0.f, 0.f, 0.f};
    const long long i = (long long)blockIdx.x * blockDim.x + threadIdx.x;
    if (i < n4) __builtin_nontemporal_store(z4, mz + i);
}

// Scatter the one-hot ones (after all zeroing is globally done).
__global__ void scatter_kernel(float* __restrict__ out)
{
    const int p = blockIdx.x * blockDim.x + threadIdx.x;
    if (p < (int)IDX_ELEMS) {
        const int idx = (int)out[p];
        out[MASK_OFF + (size_t)p * SEQ + idx] = 1.0f;
    }
}

extern "C" void kernel_launch(void* const* d_in, const int* in_sizes, int n_in,
                              void* d_out, int out_size, void* d_ws, size_t ws_size,
                              hipStream_t stream)
{
    const float* hidden = (const float*)d_in[0];
    const float* weight = (const float*)d_in[1];
    float* out = (float*)d_out;

    // Affinity scratch [b][e][s] fp32 = 1 MB. Prefer d_ws; else borrow the
    // mask tail (excluded from the fused zero, re-zeroed after the sort).
    const bool use_ws = (ws_size >= AFF_ELEMS * sizeof(float));
    float* aff = use_ws ? (float*)d_ws
                        : (out + MASK_OFF + MASK_ELEMS - AFF_ELEMS);

    gating_kernel<<<2048, 128, 0, stream>>>(hidden, weight, aff);

    const long long zero_elems = use_ws ? (long long)MASK_ELEMS
                                        : (long long)(MASK_ELEMS - AFF_ELEMS);
    topk_zero_kernel<<<ROWS + 1984, 1024, 0, stream>>>(aff, out, zero_elems);

    if (!use_ws)
        tailzero_kernel<<<256, 256, 0, stream>>>(out);

    scatter_kernel<<<(int)((IDX_ELEMS + 255) / 256), 256, 0, stream>>>(out);
}

// Round 4
// 639.997 us; speedup vs baseline: 1.0633x; 1.0226x over previous
//
#include <hip/hip_runtime.h>

constexpr int BSZ = 8, SEQ = 4096, HID = 1024, NE = 8, CAP = 512;
constexpr int ROWS = BSZ * NE;                          // 64
constexpr size_t IDX_ELEMS = (size_t)ROWS * CAP;        // 32768
constexpr size_t SCR_OFF = IDX_ELEMS;                   // 32768
constexpr size_t MASK_OFF = IDX_ELEMS * 2;              // 65536
constexpr size_t MASK_ELEMS = (size_t)ROWS * CAP * SEQ; // 134217728
constexpr size_t AFF_ELEMS = (size_t)ROWS * SEQ;        // 262144 floats (1 MB)

typedef float f4v __attribute__((ext_vector_type(4)));  // for nontemporal stores

// ---------------------------------------------------------------------------
// Gating — BYTE-IDENTICAL to the kernel that passed absmax=0. DO NOT TOUCH.
// ---------------------------------------------------------------------------
__global__ __launch_bounds__(128) void gating_kernel(const float* __restrict__ hidden,
                                                     const float* __restrict__ weight,
                                                     float* __restrict__ aff)
{
    __shared__ float hls[16][68]; // 16 tokens x 64-d chunk (pad to 68)
    __shared__ float wls[8][68];  // transposed weight chunk: [e][dd]
    __shared__ float lls[16][8];  // logits exchange

    const int tid = threadIdx.x;
    const int T0 = blockIdx.x * 16;
    const int t = tid >> 3;       // token within block
    const int e = tid & 7;        // expert

    float v0 = 0.f, v1 = 0.f, v2 = 0.f, v3 = 0.f; // SSE lanes j=0..3
    for (int c = 0; c < 16; ++c) {
        __syncthreads(); // protect previous chunk's reads
        // stage hidden chunk: 256 float4s, coalesced
#pragma unroll
        for (int k = 0; k < 2; ++k) {
            const int j = tid + k * 128;      // 0..255
            const int tt = j >> 4, q = j & 15;
            const float4 v = *(const float4*)(hidden + (size_t)(T0 + tt) * HID + c * 64 + 4 * q);
            *(float4*)&hls[tt][4 * q] = v;
        }
        // stage weight chunk transposed: 512 scalars, coalesced global reads
#pragma unroll
        for (int k = 0; k < 4; ++k) {
            const int j = tid + k * 128;      // 0..511 == dd*8+ee
            const int dd = j >> 3, ee = j & 7;
            wls[ee][dd] = weight[(size_t)(c * 64 + dd) * NE + ee];
        }
        __syncthreads();
        // four 16-float blocks per chunk, numpy SOP order
#pragma unroll
        for (int k = 0; k < 4; ++k) {
            const int base = 16 * k;
            const float4 hA = *(const float4*)&hls[t][base + 0];
            const float4 hB = *(const float4*)&hls[t][base + 4];
            const float4 hC = *(const float4*)&hls[t][base + 8];
            const float4 hD = *(const float4*)&hls[t][base + 12];
            const float4 wA = *(const float4*)&wls[e][base + 0];
            const float4 wB = *(const float4*)&wls[e][base + 4];
            const float4 wC = *(const float4*)&wls[e][base + 8];
            const float4 wD = *(const float4*)&wls[e][base + 12];
            // v = a0*b0 + (a1*b1 + (a2*b2 + (a3*b3 + v))), per lane, no FMA
            v0 = __fadd_rn(__fmul_rn(hA.x, wA.x),
                 __fadd_rn(__fmul_rn(hB.x, wB.x),
                 __fadd_rn(__fmul_rn(hC.x, wC.x),
                 __fadd_rn(__fmul_rn(hD.x, wD.x), v0))));
            v1 = __fadd_rn(__fmul_rn(hA.y, wA.y),
                 __fadd_rn(__fmul_rn(hB.y, wB.y),
                 __fadd_rn(__fmul_rn(hC.y, wC.y),
                 __fadd_rn(__fmul_rn(hD.y, wD.y), v1))));
            v2 = __fadd_rn(__fmul_rn(hA.z, wA.z),
                 __fadd_rn(__fmul_rn(hB.z, wB.z),
                 __fadd_rn(__fmul_rn(hC.z, wC.z),
                 __fadd_rn(__fmul_rn(hD.z, wD.z), v2))));
            v3 = __fadd_rn(__fmul_rn(hA.w, wA.w),
                 __fadd_rn(__fmul_rn(hB.w, wB.w),
                 __fadd_rn(__fmul_rn(hC.w, wC.w),
                 __fadd_rn(__fmul_rn(hD.w, wD.w), v3))));
        }
    }
    // npyv_sum_f32 with SSE3 (manylinux baseline): double hadd = (v0+v1)+(v2+v3)
    const float logit = __fadd_rn(__fadd_rn(v0, v1), __fadd_rn(v2, v3));

    lls[t][e] = logit;
    __syncthreads();

    float l[8];
#pragma unroll
    for (int k = 0; k < 8; ++k) l[k] = lls[t][k];
    float m = l[0];
#pragma unroll
    for (int k = 1; k < 8; ++k) m = fmaxf(m, l[k]);
    float p[8];
#pragma unroll
    for (int k = 0; k < 8; ++k)
        p[k] = (float)exp((double)__fsub_rn(l[k], m)); // correctly-rounded fp32 exp
    const float s = __fadd_rn(__fadd_rn(__fadd_rn(p[0], p[1]), __fadd_rn(p[2], p[3])),
                              __fadd_rn(__fadd_rn(p[4], p[5]), __fadd_rn(p[6], p[7])));
    const float a = __fdiv_rn(p[e], s);

    const int token = T0 + t;
    const int b = token >> 12;
    const int sidx = token & (SEQ - 1);
    aff[((size_t)b * NE + e) * SEQ + sidx] = a;
}

// ---------------------------------------------------------------------------
// FAST PATH (aff in d_ws): fully self-contained per-row kernel. Block r:
//   1) load row r's 4096 keys to LDS (bit-identical packing),
//   2) bitonic sort (identical CE order) with ~7 nontemporal zero-stores per
//      thread per pass into its OWN 8 MB mask region (512 f4/thread total;
//      stores are value-neutral and touch no LDS),
//   3) __syncthreads (drains vmcnt -> all zeros complete),
//   4) write indices/scores and scatter its own 512 ones.
// No cross-block dependencies; zeroing rides under sort barrier latency.
// ---------------------------------------------------------------------------
__global__ __launch_bounds__(1024) void sortzero_kernel(const float* __restrict__ aff,
                                                        float* __restrict__ out)
{
    __shared__ unsigned long long keys[SEQ]; // 32 KB
    const int row = blockIdx.x;
    const float* a = aff + (size_t)row * SEQ;
    float* mrow = out + MASK_OFF + (size_t)row * CAP * SEQ; // 8 MB own region

    for (int i = threadIdx.x; i < SEQ; i += 1024) {
        const unsigned int fb = __float_as_uint(a[i]);
        keys[i] = ((unsigned long long)fb << 32) | (unsigned int)(SEQ - 1 - i);
    }

    f4v* mz = (f4v*)mrow;                 // 524288 f4s; thread covers 512
    const f4v z4 = {0.f, 0.f, 0.f, 0.f};
    int zi = 0;                           // zero-store iteration 0..511

    for (int len = 2; len <= SEQ; len <<= 1) {
        for (int stride = len >> 1; stride > 0; stride >>= 1) {
            __syncthreads();
            // fire-and-forget zero stores (78 passes x 7 = 546 >= 512)
#pragma unroll
            for (int k = 0; k < 7; ++k) {
                if (zi < 512) {
                    __builtin_nontemporal_store(z4, mz + (size_t)zi * 1024 + threadIdx.x);
                    ++zi;
                }
            }
            for (int t = threadIdx.x; t < SEQ / 2; t += 1024) {
                const int i = (t << 1) - (t & (stride - 1));
                const int j = i + stride;
                const unsigned long long ki = keys[i], kj = keys[j];
                const bool desc = ((i & len) == 0);
                if (desc ? (ki < kj) : (ki > kj)) { keys[i] = kj; keys[j] = ki; }
            }
        }
    }
    __syncthreads(); // drains all zero stores (vmcnt 0) + sort visibility
    if (threadIdx.x < CAP) {
        const int t = threadIdx.x;
        const unsigned long long k = keys[t];
        const int idx = (SEQ - 1) - (int)(unsigned int)(k & 0xffffffffu);
        out[(size_t)row * CAP + t] = (float)idx;                      // indices
        out[SCR_OFF + (size_t)row * CAP + t] =
            __uint_as_float((unsigned int)(k >> 32));                 // scores
        mrow[(size_t)t * SEQ + idx] = 1.0f;                           // one-hot
    }
}

// ---------------------------------------------------------------------------
// FALLBACK PATH (no usable d_ws): R3 structure, byte-identical behavior.
// ---------------------------------------------------------------------------
__global__ __launch_bounds__(1024) void topk_zero_kernel(const float* __restrict__ aff,
                                                         float* __restrict__ out,
                                                         long long zero_elems)
{
    __shared__ unsigned long long keys[SEQ]; // 32 KB
    if (blockIdx.x < (unsigned)ROWS) {
        const int row = blockIdx.x;
        const float* a = aff + (size_t)row * SEQ;
        for (int i = threadIdx.x; i < SEQ; i += 1024) {
            const unsigned int fb = __float_as_uint(a[i]);
            keys[i] = ((unsigned long long)fb << 32) | (unsigned int)(SEQ - 1 - i);
        }
        for (int len = 2; len <= SEQ; len <<= 1) {
            for (int stride = len >> 1; stride > 0; stride >>= 1) {
                __syncthreads();
                for (int t = threadIdx.x; t < SEQ / 2; t += 1024) {
                    const int i = (t << 1) - (t & (stride - 1));
                    const int j = i + stride;
                    const unsigned long long ki = keys[i], kj = keys[j];
                    const bool desc = ((i & len) == 0);
                    if (desc ? (ki < kj) : (ki > kj)) { keys[i] = kj; keys[j] = ki; }
                }
            }
        }
        __syncthreads();
        if (threadIdx.x < CAP) {
            const int t = threadIdx.x;
            const unsigned long long k = keys[t];
            const int idx = (SEQ - 1) - (int)(unsigned int)(k & 0xffffffffu);
            out[(size_t)row * CAP + t] = (float)idx;                         // indices
            out[SCR_OFF + (size_t)row * CAP + t] =
                __uint_as_float((unsigned int)(k >> 32));                    // scores
        }
    } else {
        const long long nz4 = zero_elems >> 2;
        f4v* mz = (f4v*)(out + MASK_OFF);
        const f4v z4 = {0.f, 0.f, 0.f, 0.f};
        const long long stride = (long long)(gridDim.x - ROWS) * 1024;
        for (long long i = (long long)(blockIdx.x - ROWS) * 1024 + threadIdx.x;
             i < nz4; i += stride)
            __builtin_nontemporal_store(z4, mz + i);
    }
}

__global__ void tailzero_kernel(float* __restrict__ out)
{
    const long long n4 = (long long)(AFF_ELEMS >> 2); // 65536 float4s
    f4v* mz = (f4v*)(out + MASK_OFF + MASK_ELEMS - AFF_ELEMS);
    const f4v z4 = {0.f, 0.f, 0.f, 0.f};
    const long long i = (long long)blockIdx.x * blockDim.x + threadIdx.x;
    if (i < n4) __builtin_nontemporal_store(z4, mz + i);
}

__global__ void scatter_kernel(float* __restrict__ out)
{
    const int p = blockIdx.x * blockDim.x + threadIdx.x;
    if (p < (int)IDX_ELEMS) {
        const int idx = (int)out[p];
        out[MASK_OFF + (size_t)p * SEQ + idx] = 1.0f;
    }
}

extern "C" void kernel_launch(void* const* d_in, const int* in_sizes, int n_in,
                              void* d_out, int out_size, void* d_ws, size_t ws_size,
                              hipStream_t stream)
{
    const float* hidden = (const float*)d_in[0];
    const float* weight = (const float*)d_in[1];
    float* out = (float*)d_out;

    const bool use_ws = (ws_size >= AFF_ELEMS * sizeof(float));

    if (use_ws) {
        float* aff = (float*)d_ws;
        gating_kernel<<<2048, 128, 0, stream>>>(hidden, weight, aff);
        sortzero_kernel<<<ROWS, 1024, 0, stream>>>(aff, out);
    } else {
        // aff borrows the mask tail; proven R3 path (sort can't overlap with
        // self-owned zeroing here because all aff rows live in row 63's mask).
        float* aff = out + MASK_OFF + MASK_ELEMS - AFF_ELEMS;
        gating_kernel<<<2048, 128, 0, stream>>>(hidden, weight, aff);
        const long long zero_elems = (long long)(MASK_ELEMS - AFF_ELEMS);
        topk_zero_kernel<<<ROWS + 1984, 1024, 0, stream>>>(aff, out, zero_elems);
        tailzero_kernel<<<256, 256, 0, stream>>>(out);
        scatter_kernel<<<(int)((IDX_ELEMS + 255) / 256), 256, 0, stream>>>(out);
    }
}